// Round 7
// baseline (251.107 us; speedup 1.0000x reference)
//
#include <hip/hip_runtime.h>
#include <math.h>

#define C_CH       64
#define F_FRAMES   999
#define TOTAL_SAMP 320000
#define FRAME_LEN  640
#define STEP       320
#define N2         512      // complex FFT size (real FFT 1024)
#define NBINS      513
#define NMEL       40
#define NMFCC      13
#define NWAVE      (C_CH * F_FRAMES)    // 63936 waves, one per (channel, frame)
#define NBLK       (NWAVE / 4)          // 15984 blocks, divisible by 8
#define MELW_STRIDE 72      // multiple of 4; max (len + lo%4) observed ~63
#define SPAD       576      // 512 + 64 pad float2 per wave

#define TWO_PI_F 6.28318530717958647692f

// d_ws float layout (all offsets multiples of 4 -> float4-aligned)
#define WS_HANN   0        // 640
#define WS_DCT    640      // 520
#define WS_MSTART 1160     // 40 ints (lo4, 4-aligned bin start)
#define WS_MELW   1200     // 40*72 = 2880, zero-padded rows
#define WS_TOTAL  4080

__global__ __launch_bounds__(256)
void setup_tables(float* __restrict__ ws) {
    __shared__ float wloc[NBINS];
    __shared__ int   chloc[NBINS];
    __shared__ int   lo4_s[NMEL];
    const int tid = threadIdx.x;

    for (int n = tid; n < FRAME_LEN; n += 256)
        ws[WS_HANN + n] = 0.5f - 0.5f * cosf((float)n * (TWO_PI_F / 640.0f));

    for (int idx = tid; idx < NMFCC * NMEL; idx += 256) {
        int j = idx / NMEL, m = idx - j * NMEL;
        ws[WS_DCT + idx] = 0.223606797749978969f *
            cosf((float)(M_PI * (double)j * ((double)m + 0.5) / (double)NMEL));
    }

    // zero-fill mel weight rows (read fully as 18 x float4 later)
    for (int idx = tid; idx < NMEL * MELW_STRIDE; idx += 256)
        ws[WS_MELW + idx] = 0.0f;

    // dense per-bin (ch, w), replicating TF MfccMelFilterbank
    const double mel_lo  = 1127.0 * log1p(20.0 / 700.0);
    const double mel_hi  = 1127.0 * log1p(7600.0 / 700.0);
    const double spacing = (mel_hi - mel_lo) / (NMEL + 1);
    for (int i = tid; i < NBINS; i += 256) {
        if (i < 2 || i > 486) {      // start_index=2, end_index=486
            chloc[i] = -100; wloc[i] = 0.0f;
        } else {
            double melf = 1127.0 * log1p((double)i * 15.625 / 700.0);
            int ch = 0;
            while (ch < NMEL && (mel_lo + spacing * (ch + 1)) < melf) ch++;
            ch -= 1;                 // may be -1
            chloc[i] = ch;
            wloc[i]  = (float)((mel_lo + spacing * (ch + 2) - melf) / spacing);
        }
    }
    __syncthreads();

    // per-channel lo (channel m receives bins with ch in {m-1, m}); store lo4 = lo & ~3
    if (tid < NMEL) {
        int lo = -1;
        for (int i = 2; i <= 486; ++i) {
            int ch = chloc[i];
            if (ch == tid || ch + 1 == tid) { if (lo < 0) { lo = i; break; } }
        }
        int lo4 = (lo >= 0) ? (lo & ~3) : 0;
        lo4_s[tid] = lo4;
        ((int*)(ws + WS_MSTART))[tid] = lo4;
    }
    __syncthreads();

    // scatter weights: each bin writes its <=2 contributions at (i - lo4[ch])
    for (int i = 2 + tid; i <= 486; i += 256) {
        int ch = chloc[i]; float wgt = wloc[i];
        if (ch >= 0)
            ws[WS_MELW + ch * MELW_STRIDE + (i - lo4_s[ch])] = wgt;
        if (ch + 1 < NMEL)
            ws[WS_MELW + (ch + 1) * MELW_STRIDE + (i - lo4_s[ch + 1])] = 1.0f - wgt;
    }
}

__device__ __forceinline__ float2 cadd(float2 a, float2 b){ return make_float2(a.x+b.x, a.y+b.y); }
__device__ __forceinline__ float2 csub(float2 a, float2 b){ return make_float2(a.x-b.x, a.y-b.y); }
__device__ __forceinline__ float2 cmul(float2 a, float2 w){ return make_float2(a.x*w.x - a.y*w.y, a.x*w.y + a.y*w.x); }
__device__ __forceinline__ float2 mulnegi(float2 a){ return make_float2(a.y, -a.x); }   // a * (-i)

// forward 8-pt DFT in registers (DIT): out[k] = sum_r v[r] W8^{rk}
__device__ __forceinline__ void dft8(float2 v[8]) {
    const float s = 0.70710678118654752440f;
    float2 b0=cadd(v[0],v[4]), b4=csub(v[0],v[4]);
    float2 b1=cadd(v[1],v[5]), b5=csub(v[1],v[5]);
    float2 b2=cadd(v[2],v[6]), b6=csub(v[2],v[6]);
    float2 b3=cadd(v[3],v[7]), b7=csub(v[3],v[7]);
    float2 c0=cadd(b0,b2), c2=csub(b0,b2);
    float2 c1=cadd(b1,b3), c3=csub(b1,b3);
    float2 t6=mulnegi(b6);
    float2 c4=cadd(b4,t6), c6=csub(b4,t6);
    float2 t7=mulnegi(b7);
    float2 c5=cadd(b5,t7), c7=csub(b5,t7);
    float2 t3=mulnegi(c3);
    float2 w1c5 = make_float2(s*(c5.x+c5.y), s*(c5.y-c5.x));   // W8^1 * c5
    float2 w3c7 = make_float2(s*(c7.y-c7.x), -s*(c7.x+c7.y));  // W8^3 * c7
    v[0]=cadd(c0,c1);   v[4]=csub(c0,c1);
    v[2]=cadd(c2,t3);   v[6]=csub(c2,t3);
    v[1]=cadd(c4,w1c5); v[5]=csub(c4,w1c5);
    v[3]=cadd(c6,w3c7); v[7]=csub(c6,w3c7);
}

// apply W^r, r=1..7, with log-depth power ladder (base w = e^{-i a})
__device__ __forceinline__ void twiddle7(float2 v[8], float2 w1) {
    float2 w2 = cmul(w1, w1);
    float2 w3 = cmul(w2, w1);
    float2 w4 = cmul(w2, w2);
    float2 w5 = cmul(w3, w2);
    float2 w6 = cmul(w3, w3);
    float2 w7 = cmul(w4, w3);
    v[1] = cmul(v[1], w1); v[2] = cmul(v[2], w2); v[3] = cmul(v[3], w3);
    v[4] = cmul(v[4], w4); v[5] = cmul(v[5], w5); v[6] = cmul(v[6], w6);
    v[7] = cmul(v[7], w7);
}

__global__ __launch_bounds__(256, 8)
void mfcc_kernel(const float* __restrict__ wave, const float* __restrict__ ws,
                 float* __restrict__ out) {
    __shared__ __align__(16) float2 fftbuf[4 * SPAD];   // 18432 B
    __shared__ __align__(16) float  lmall[4 * NMEL];    // 640 B

    const int tid = threadIdx.x;
    // XCD-bijective swizzle: 15984 % 8 == 0; each XCD gets a contiguous range
    const int b    = blockIdx.x;
    const int bs   = (b & 7) * (NBLK / 8) + (b >> 3);
    const int w    = tid >> 6;           // wave id 0..3
    const int l    = tid & 63;           // lane
    const int g    = bs * 4 + w;         // global wave id 0..63935
    const int c    = g & 63;             // channel: block's 4 waves = 4 adjacent channels
    const int f    = g >> 6;             // frame 0..998 (same for all 4 waves; 4|g so no wrap)

    // ---- fully wave-independent: no barriers anywhere ----
    float2* S    = fftbuf + w * SPAD;
    float*  magf = (float*)S;            // overlaid after FFT is consumed
    float*  lm   = lmall + w * NMEL;
    const float2* hann2 = (const float2*)(ws + WS_HANN);

    // per-lane twiddle bases (frame-independent): W = e^{-i theta} = (cos, -sin)
    float s2a, c2a, s3a, c3a, sua, cua;
    __sincosf((float)(l & 7) * (TWO_PI_F / 64.0f),  &s2a, &c2a);
    __sincosf((float)l       * (TWO_PI_F / 512.0f), &s3a, &c3a);
    __sincosf((float)l       * (TWO_PI_F / 1024.0f),&sua, &cua);
    const float2 tb2 = make_float2(c2a, -s2a);
    const float2 tb3 = make_float2(c3a, -s3a);
    const float2 bu  = make_float2(cua, -sua);

    float2 v[8];
    // ---- gather + window straight into registers (frame base + strided t) ----
    {
        const float* wp = wave + (size_t)f * STEP * C_CH + c;
        #pragma unroll
        for (int r = 0; r < 8; ++r) {
            if (r < 5) {                  // 320 complex = 640 real samples
                const int i  = l + 64 * r;
                float x0 = wp[(size_t)(2 * i)     * C_CH];
                float x1 = wp[(size_t)(2 * i + 1) * C_CH];
                float2 h = hann2[i];
                v[r] = make_float2(x0 * h.x, x1 * h.y);
            } else v[r] = make_float2(0.f, 0.f);
        }
    }

    // ---- stage 1 (Ns=1): radix-8, no twiddle ----
    dft8(v);
    #pragma unroll
    for (int k = 0; k < 8; ++k) { const int i = 8 * l + k; S[i + (i >> 3)] = v[k]; }

    // ---- stage 2 (Ns=8): twiddle W64^{(l&7) r} ----
    #pragma unroll
    for (int r = 0; r < 8; ++r) { const int i = l + 64 * r; v[r] = S[i + (i >> 3)]; }
    twiddle7(v, tb2);
    dft8(v);
    {
        const int idxD = ((l >> 3) << 6) + (l & 7);
        #pragma unroll
        for (int k = 0; k < 8; ++k) { const int i = idxD + 8 * k; S[i + (i >> 3)] = v[k]; }
    }

    // ---- stage 3 (Ns=64): twiddle W512^{l r}; result stays in registers ----
    #pragma unroll
    for (int r = 0; r < 8; ++r) { const int i = l + 64 * r; v[r] = S[i + (i >> 3)]; }
    twiddle7(v, tb3);
    dft8(v);
    // lane l now holds Z[l + 64k] in v[k] (natural order)

    // ---- conjugate partner via cross-lane shuffle: Z[(512-k)&511] ----
    // for l>0: partner(reg r) = lane (64-l), reg (7-r); l==0: own reg (8-r)&7
    float2 Zm[8];
    const int src = (64 - l) & 63;
    #pragma unroll
    for (int r = 0; r < 8; ++r) {
        Zm[r].x = __shfl(v[7 - r].x, src);
        Zm[r].y = __shfl(v[7 - r].y, src);
    }
    if (l == 0) {
        #pragma unroll
        for (int r = 0; r < 8; ++r) Zm[r] = v[(8 - r) & 7];
    }

    // ---- real-FFT unpack + magnitude ----
    // W16^r = (cos(pi r/8), -sin(pi r/8))
    const float C16[8] = {1.0f, 0.923879533f, 0.707106781f, 0.382683432f,
                          0.0f, -0.382683432f, -0.707106781f, -0.923879533f};
    const float S16[8] = {0.0f, 0.382683432f, 0.707106781f, 0.923879533f,
                          1.0f, 0.923879533f, 0.707106781f, 0.382683432f};
    float m8[8];
    #pragma unroll
    for (int r = 0; r < 8; ++r) {
        float2 Zk = v[r];
        float Er = 0.5f * (Zk.x + Zm[r].x);
        float Ei = 0.5f * (Zk.y - Zm[r].y);
        float Or = 0.5f * (Zk.y + Zm[r].y);
        float Oi = -0.5f * (Zk.x - Zm[r].x);
        float2 tw = cmul(bu, make_float2(C16[r], -S16[r]));   // W1024^{l+64r}
        float Xr = Er + tw.x * Or - tw.y * Oi;
        float Xi = Ei + tw.x * Oi + tw.y * Or;
        m8[r] = sqrtf(Xr * Xr + Xi * Xi);
    }
    #pragma unroll
    for (int r = 0; r < 8; ++r) magf[l + 64 * r] = m8[r];
    if (l == 0) magf[512] = fabsf(v[0].x - v[0].y);   // X[512] = Z0.re - Z0.im

    // ---- mel via zero-padded CSR rows: 18 x float4 dot, branch-free ----
    if (l < NMEL) {
        const int lo4 = ((const int*)(ws + WS_MSTART))[l];
        const float4* wrow = (const float4*)(ws + WS_MELW + l * MELW_STRIDE);
        const float4* mrow = (const float4*)(magf + lo4);
        float acc = 0.0f;
        #pragma unroll
        for (int j = 0; j < MELW_STRIDE / 4; ++j) {
            float4 wv = wrow[j], mv = mrow[j];
            acc += wv.x * mv.x + wv.y * mv.y + wv.z * mv.z + wv.w * mv.w;
        }
        lm[l] = logf(acc + 1e-12f);
    }

    // ---- DCT + clip + store (lanes 0..12), float4 ----
    if (l < NMFCC) {
        const float4* drow = (const float4*)(ws + WS_DCT + l * NMEL);
        const float4* lrow = (const float4*)lm;
        float acc = 0.0f;
        #pragma unroll
        for (int j = 0; j < NMEL / 4; ++j) {
            float4 dv = drow[j], lv = lrow[j];
            acc += dv.x * lv.x + dv.y * lv.y + dv.z * lv.z + dv.w * lv.w;
        }
        acc = fminf(10.0f, fmaxf(-10.0f, acc));
        out[((size_t)c * F_FRAMES + f) * NMFCC + l] = acc;
    }
}

extern "C" void kernel_launch(void* const* d_in, const int* in_sizes, int n_in,
                              void* d_out, int out_size, void* d_ws, size_t ws_size,
                              hipStream_t stream) {
    const float* wave = (const float*)d_in[0];
    float* out = (float*)d_out;
    float* ws  = (float*)d_ws;
    hipLaunchKernelGGL(setup_tables, dim3(1), dim3(256), 0, stream, ws);
    hipLaunchKernelGGL(mfcc_kernel, dim3(NBLK), dim3(256), 0, stream, wave, ws, out);
}

// Round 8
// 177.599 us; speedup vs baseline: 1.4139x; 1.4139x over previous
//
#include <hip/hip_runtime.h>
#include <hip/hip_fp16.h>
#include <math.h>

#define C_CH       64
#define F_FRAMES   999
#define TOTAL_SAMP 320000
#define FRAME_LEN  640
#define STEP       320
#define N2         512      // complex FFT size (real FFT 1024)
#define NBINS      513
#define NMEL       40
#define NMFCC      13
#define CHPG       16       // channels per block (one 64B line)
#define NCHG       4        // channel groups
#define NBLK       (F_FRAMES * NCHG)   // 3996 blocks
#define MELW_STRIDE 72      // multiple of 4
#define SPAD       576      // 512 + 64 pad float2 per wave
#define SSTR       654      // halfs per channel row (640 + pad, even)

#define TWO_PI_F 6.28318530717958647692f

// d_ws float layout (all offsets multiples of 4 -> float4-aligned)
#define WS_HANN   0        // 640
#define WS_DCT    640      // 520
#define WS_MSTART 1160     // 40 ints (lo4, 4-aligned bin start)
#define WS_MELW   1200     // 40*72 = 2880, zero-padded rows
#define WS_TOTAL  4080

__global__ __launch_bounds__(256)
void setup_tables(float* __restrict__ ws) {
    __shared__ float wloc[NBINS];
    __shared__ int   chloc[NBINS];
    __shared__ int   lo4_s[NMEL];
    const int tid = threadIdx.x;

    for (int n = tid; n < FRAME_LEN; n += 256)
        ws[WS_HANN + n] = 0.5f - 0.5f * cosf((float)n * (TWO_PI_F / 640.0f));

    for (int idx = tid; idx < NMFCC * NMEL; idx += 256) {
        int j = idx / NMEL, m = idx - j * NMEL;
        ws[WS_DCT + idx] = 0.223606797749978969f *
            cosf((float)(M_PI * (double)j * ((double)m + 0.5) / (double)NMEL));
    }

    // zero-fill mel weight rows (read fully as 18 x float4 later)
    for (int idx = tid; idx < NMEL * MELW_STRIDE; idx += 256)
        ws[WS_MELW + idx] = 0.0f;

    // dense per-bin (ch, w), replicating TF MfccMelFilterbank
    const double mel_lo  = 1127.0 * log1p(20.0 / 700.0);
    const double mel_hi  = 1127.0 * log1p(7600.0 / 700.0);
    const double spacing = (mel_hi - mel_lo) / (NMEL + 1);
    for (int i = tid; i < NBINS; i += 256) {
        if (i < 2 || i > 486) {      // start_index=2, end_index=486
            chloc[i] = -100; wloc[i] = 0.0f;
        } else {
            double melf = 1127.0 * log1p((double)i * 15.625 / 700.0);
            int ch = 0;
            while (ch < NMEL && (mel_lo + spacing * (ch + 1)) < melf) ch++;
            ch -= 1;                 // may be -1
            chloc[i] = ch;
            wloc[i]  = (float)((mel_lo + spacing * (ch + 2) - melf) / spacing);
        }
    }
    __syncthreads();

    // per-channel lo (channel m receives bins with ch in {m-1, m}); store lo4 = lo & ~3
    if (tid < NMEL) {
        int lo = -1;
        for (int i = 2; i <= 486; ++i) {
            int ch = chloc[i];
            if (ch == tid || ch + 1 == tid) { if (lo < 0) { lo = i; break; } }
        }
        int lo4 = (lo >= 0) ? (lo & ~3) : 0;
        lo4_s[tid] = lo4;
        ((int*)(ws + WS_MSTART))[tid] = lo4;
    }
    __syncthreads();

    // scatter weights: each bin writes its <=2 contributions at (i - lo4[ch])
    for (int i = 2 + tid; i <= 486; i += 256) {
        int ch = chloc[i]; float wgt = wloc[i];
        if (ch >= 0)
            ws[WS_MELW + ch * MELW_STRIDE + (i - lo4_s[ch])] = wgt;
        if (ch + 1 < NMEL)
            ws[WS_MELW + (ch + 1) * MELW_STRIDE + (i - lo4_s[ch + 1])] = 1.0f - wgt;
    }
}

__device__ __forceinline__ float2 cadd(float2 a, float2 b){ return make_float2(a.x+b.x, a.y+b.y); }
__device__ __forceinline__ float2 csub(float2 a, float2 b){ return make_float2(a.x-b.x, a.y-b.y); }
__device__ __forceinline__ float2 cmul(float2 a, float2 w){ return make_float2(a.x*w.x - a.y*w.y, a.x*w.y + a.y*w.x); }
__device__ __forceinline__ float2 mulnegi(float2 a){ return make_float2(a.y, -a.x); }   // a * (-i)

// forward 8-pt DFT in registers (DIT): out[k] = sum_r v[r] W8^{rk}
__device__ __forceinline__ void dft8(float2 v[8]) {
    const float s = 0.70710678118654752440f;
    float2 b0=cadd(v[0],v[4]), b4=csub(v[0],v[4]);
    float2 b1=cadd(v[1],v[5]), b5=csub(v[1],v[5]);
    float2 b2=cadd(v[2],v[6]), b6=csub(v[2],v[6]);
    float2 b3=cadd(v[3],v[7]), b7=csub(v[3],v[7]);
    float2 c0=cadd(b0,b2), c2=csub(b0,b2);
    float2 c1=cadd(b1,b3), c3=csub(b1,b3);
    float2 t6=mulnegi(b6);
    float2 c4=cadd(b4,t6), c6=csub(b4,t6);
    float2 t7=mulnegi(b7);
    float2 c5=cadd(b5,t7), c7=csub(b5,t7);
    float2 t3=mulnegi(c3);
    float2 w1c5 = make_float2(s*(c5.x+c5.y), s*(c5.y-c5.x));   // W8^1 * c5
    float2 w3c7 = make_float2(s*(c7.y-c7.x), -s*(c7.x+c7.y));  // W8^3 * c7
    v[0]=cadd(c0,c1);   v[4]=csub(c0,c1);
    v[2]=cadd(c2,t3);   v[6]=csub(c2,t3);
    v[1]=cadd(c4,w1c5); v[5]=csub(c4,w1c5);
    v[3]=cadd(c6,w3c7); v[7]=csub(c6,w3c7);
}

// apply W^r, r=1..7, with log-depth power ladder (base w = e^{-i a})
__device__ __forceinline__ void twiddle7(float2 v[8], float2 w1) {
    float2 w2 = cmul(w1, w1);
    float2 w3 = cmul(w2, w1);
    float2 w4 = cmul(w2, w2);
    float2 w5 = cmul(w3, w2);
    float2 w6 = cmul(w3, w3);
    float2 w7 = cmul(w4, w3);
    v[1] = cmul(v[1], w1); v[2] = cmul(v[2], w2); v[3] = cmul(v[3], w3);
    v[4] = cmul(v[4], w4); v[5] = cmul(v[5], w5); v[6] = cmul(v[6], w6);
    v[7] = cmul(v[7], w7);
}

__global__ __launch_bounds__(256, 4)
void mfcc_kernel(const float* __restrict__ wave, const float* __restrict__ ws,
                 float* __restrict__ out) {
    __shared__ __align__(16) __half samples_h[CHPG * SSTR];   // 20928 B, [ch][t] transposed
    __shared__ __align__(16) float2 fftbuf[4 * SPAD];         // 18432 B
    __shared__ __align__(16) float  lmall[4 * NMEL];          // 640 B

    const int tid = threadIdx.x;
    // bijective chunked XCD swizzle: nwg = 3996 = 8*499 + 4
    const int b    = blockIdx.x;
    const int xcd  = b & 7;
    const int wgid = (xcd < 4 ? xcd * 500 : 2000 + (xcd - 4) * 499) + (b >> 3);
    const int cg   = wgid / 999;         // channel group 0..3 (16 channels = one 64B line)
    const int f    = wgid - cg * 999;    // frame; adjacent wgids = adjacent frames (L2 overlap)
    const int c0   = cg * CHPG;
    const int w    = tid >> 6;           // wave id 0..3
    const int l    = tid & 63;           // lane

    // ---- coalesced stage: 640 rows x 64B, Hann applied, transposed to [ch][t] half ----
    {
        const float4* wp4 = (const float4*)(wave + (size_t)f * STEP * C_CH) + cg * 4;
        const float*  hannf = ws + WS_HANN;
        #pragma unroll
        for (int m = 0; m < 10; ++m) {
            const int j = tid + 256 * m;     // 0..2559
            const int t = j >> 2, g = j & 3;
            float4 x = wp4[(size_t)t * 16 + g];
            float  h = hannf[t];
            samples_h[(4*g+0)*SSTR + t] = __float2half(x.x * h);
            samples_h[(4*g+1)*SSTR + t] = __float2half(x.y * h);
            samples_h[(4*g+2)*SSTR + t] = __float2half(x.z * h);
            samples_h[(4*g+3)*SSTR + t] = __float2half(x.w * h);
        }
    }
    __syncthreads();
    // ---- below: wave-private, no more block barriers ----

    float2* S    = fftbuf + w * SPAD;
    float*  magf = (float*)S;            // overlaid after FFT is consumed
    float*  lm   = lmall + w * NMEL;

    // per-lane twiddle bases (frame-independent): W = e^{-i theta} = (cos, -sin)
    float s2a, c2a, s3a, c3a, sua, cua;
    __sincosf((float)(l & 7) * (TWO_PI_F / 64.0f),  &s2a, &c2a);
    __sincosf((float)l       * (TWO_PI_F / 512.0f), &s3a, &c3a);
    __sincosf((float)l       * (TWO_PI_F / 1024.0f),&sua, &cua);
    const float2 tb2 = make_float2(c2a, -s2a);
    const float2 tb3 = make_float2(c3a, -s3a);
    const float2 bu  = make_float2(cua, -sua);

    // W16^r = (cos(pi r/8), -sin(pi r/8))
    const float C16[8] = {1.0f, 0.923879533f, 0.707106781f, 0.382683432f,
                          0.0f, -0.382683432f, -0.707106781f, -0.923879533f};
    const float S16[8] = {0.0f, 0.382683432f, 0.707106781f, 0.923879533f,
                          1.0f, 0.923879533f, 0.707106781f, 0.382683432f};

    for (int q = 0; q < 4; ++q) {
        const int ch = 4 * w + q;        // local channel 0..15
        const __half2* sh2 = (const __half2*)samples_h + ((ch * SSTR) >> 1);

        float2 v[8];
        // ---- windowed samples (already Hann'd) straight into registers ----
        #pragma unroll
        for (int r = 0; r < 8; ++r) {
            if (r < 5) {                  // 320 complex = 640 real samples
                v[r] = __half22float2(sh2[l + 64 * r]);
            } else v[r] = make_float2(0.f, 0.f);
        }

        // ---- stage 1 (Ns=1): radix-8, no twiddle ----
        dft8(v);
        #pragma unroll
        for (int k = 0; k < 8; ++k) { const int i = 8 * l + k; S[i + (i >> 3)] = v[k]; }

        // ---- stage 2 (Ns=8): twiddle W64^{(l&7) r} ----
        #pragma unroll
        for (int r = 0; r < 8; ++r) { const int i = l + 64 * r; v[r] = S[i + (i >> 3)]; }
        twiddle7(v, tb2);
        dft8(v);
        {
            const int idxD = ((l >> 3) << 6) + (l & 7);
            #pragma unroll
            for (int k = 0; k < 8; ++k) { const int i = idxD + 8 * k; S[i + (i >> 3)] = v[k]; }
        }

        // ---- stage 3 (Ns=64): twiddle W512^{l r}; result stays in registers ----
        #pragma unroll
        for (int r = 0; r < 8; ++r) { const int i = l + 64 * r; v[r] = S[i + (i >> 3)]; }
        twiddle7(v, tb3);
        dft8(v);
        // lane l now holds Z[l + 64k] in v[k] (natural order)

        // ---- conjugate partner via cross-lane shuffle: Z[(512-k)&511] ----
        float2 Zm[8];
        const int src = (64 - l) & 63;
        #pragma unroll
        for (int r = 0; r < 8; ++r) {
            Zm[r].x = __shfl(v[7 - r].x, src);
            Zm[r].y = __shfl(v[7 - r].y, src);
        }
        if (l == 0) {
            #pragma unroll
            for (int r = 0; r < 8; ++r) Zm[r] = v[(8 - r) & 7];
        }

        // ---- real-FFT unpack + magnitude ----
        float m8[8];
        #pragma unroll
        for (int r = 0; r < 8; ++r) {
            float2 Zk = v[r];
            float Er = 0.5f * (Zk.x + Zm[r].x);
            float Ei = 0.5f * (Zk.y - Zm[r].y);
            float Or = 0.5f * (Zk.y + Zm[r].y);
            float Oi = -0.5f * (Zk.x - Zm[r].x);
            float2 tw = cmul(bu, make_float2(C16[r], -S16[r]));   // W1024^{l+64r}
            float Xr = Er + tw.x * Or - tw.y * Oi;
            float Xi = Ei + tw.x * Oi + tw.y * Or;
            m8[r] = sqrtf(Xr * Xr + Xi * Xi);
        }
        #pragma unroll
        for (int r = 0; r < 8; ++r) magf[l + 64 * r] = m8[r];
        // magf[512] = X[512] = Z0.re - Z0.im; zero 513..575 so padded mel reads are 0*0
        magf[512 + l] = (l == 0) ? fabsf(v[0].x - v[0].y) : 0.0f;

        // ---- mel via zero-padded CSR rows: 18 x float4 dot, branch-free ----
        if (l < NMEL) {
            const int lo4 = ((const int*)(ws + WS_MSTART))[l];
            const float4* wrow = (const float4*)(ws + WS_MELW + l * MELW_STRIDE);
            const float4* mrow = (const float4*)(magf + lo4);
            float acc = 0.0f;
            #pragma unroll
            for (int j = 0; j < MELW_STRIDE / 4; ++j) {
                float4 wv = wrow[j], mv = mrow[j];
                acc += wv.x * mv.x + wv.y * mv.y + wv.z * mv.z + wv.w * mv.w;
            }
            lm[l] = logf(acc + 1e-12f);
        }

        // ---- DCT + clip + store (lanes 0..12), float4 ----
        if (l < NMFCC) {
            const float4* drow = (const float4*)(ws + WS_DCT + l * NMEL);
            const float4* lrow = (const float4*)lm;
            float acc = 0.0f;
            #pragma unroll
            for (int j = 0; j < NMEL / 4; ++j) {
                float4 dv = drow[j], lv = lrow[j];
                acc += dv.x * lv.x + dv.y * lv.y + dv.z * lv.z + dv.w * lv.w;
            }
            acc = fminf(10.0f, fmaxf(-10.0f, acc));
            out[((size_t)(c0 + ch) * F_FRAMES + f) * NMFCC + l] = acc;
        }
    }
}

extern "C" void kernel_launch(void* const* d_in, const int* in_sizes, int n_in,
                              void* d_out, int out_size, void* d_ws, size_t ws_size,
                              hipStream_t stream) {
    const float* wave = (const float*)d_in[0];
    float* out = (float*)d_out;
    float* ws  = (float*)d_ws;
    hipLaunchKernelGGL(setup_tables, dim3(1), dim3(256), 0, stream, ws);
    hipLaunchKernelGGL(mfcc_kernel, dim3(NBLK), dim3(256), 0, stream, wave, ws, out);
}